// Round 5
// baseline (502.475 us; speedup 1.0000x reference)
//
#include <hip/hip_runtime.h>
#include <math.h>

#define N_NODES 100000
#define N_EDGES 1600000
#define IN_DIM  128
#define HD      64     // HEADS * OUT_DIM
#define HEADS   4
#define ODIM    16
#define NEG_SLOPE 0.2f

#define BSH 8                                   // nodes per bucket = 256
#define NB  ((N_NODES + 255) >> 8)              // 391 buckets
#define PART_BLOCKS 256
#define EPB ((N_EDGES + PART_BLOCKS - 1) / PART_BLOCKS)   // 6250
#define MAT (NB * PART_BLOCKS)                  // 100096
#define CAP 12288                               // LDS stage cap per bucket (mean 4092, sigma 64)

// ---------------------------------------------------------------------------
// Kernel 1: h = feat @ W  + fused el/er epilogue.
// ---------------------------------------------------------------------------
__global__ __launch_bounds__(256) void k_gemm_fused(const float* __restrict__ feat,
                                                    const float* __restrict__ W,
                                                    const float* __restrict__ attn_l,
                                                    const float* __restrict__ attn_r,
                                                    float* __restrict__ hws,
                                                    float* __restrict__ el,
                                                    float* __restrict__ er) {
    __shared__ float sF[64][IN_DIM];
    __shared__ float sW[IN_DIM][HD];

    const int tid  = threadIdx.x;
    const int base = blockIdx.x * 64;

    for (int i = tid; i < IN_DIM * HD; i += 256) sW[i >> 6][i & 63] = W[i];
    for (int i = tid; i < 64 * IN_DIM; i += 256) {
        int n = i >> 7, k = i & 127;
        int gn = base + n;
        sF[n][k] = (gn < N_NODES) ? feat[gn * IN_DIM + k] : 0.f;
    }
    __syncthreads();

    const int cg = (tid & 15) * 4;
    const int rg = (tid >> 4) * 4;

    float acc[4][4] = {};
    for (int k = 0; k < IN_DIM; k += 4) {
        float4 w0 = *(const float4*)&sW[k + 0][cg];
        float4 w1 = *(const float4*)&sW[k + 1][cg];
        float4 w2 = *(const float4*)&sW[k + 2][cg];
        float4 w3 = *(const float4*)&sW[k + 3][cg];
        #pragma unroll
        for (int r = 0; r < 4; ++r) {
            float4 f = *(const float4*)&sF[rg + r][k];
            acc[r][0] += f.x * w0.x + f.y * w1.x + f.z * w2.x + f.w * w3.x;
            acc[r][1] += f.x * w0.y + f.y * w1.y + f.z * w2.y + f.w * w3.y;
            acc[r][2] += f.x * w0.z + f.y * w1.z + f.z * w2.z + f.w * w3.z;
            acc[r][3] += f.x * w0.w + f.y * w1.w + f.z * w2.w + f.w * w3.w;
        }
    }

    #pragma unroll
    for (int r = 0; r < 4; ++r) {
        int gn = base + rg + r;
        if (gn < N_NODES) {
            *(float4*)&hws[gn * HD + cg] =
                make_float4(acc[r][0], acc[r][1], acc[r][2], acc[r][3]);
        }
    }

    float4 al = *(const float4*)&attn_l[cg];
    float4 ar = *(const float4*)&attn_r[cg];
    const int head = (tid & 15) >> 2;
    #pragma unroll
    for (int r = 0; r < 4; ++r) {
        float pl = acc[r][0]*al.x + acc[r][1]*al.y + acc[r][2]*al.z + acc[r][3]*al.w;
        float pr = acc[r][0]*ar.x + acc[r][1]*ar.y + acc[r][2]*ar.z + acc[r][3]*ar.w;
        pl += __shfl_xor(pl, 1); pl += __shfl_xor(pl, 2);
        pr += __shfl_xor(pr, 1); pr += __shfl_xor(pr, 2);
        int gn = base + rg + r;
        if ((tid & 3) == 0 && gn < N_NODES) {
            el[gn * HEADS + head] = pl;
            er[gn * HEADS + head] = pr;
        }
    }
}

// ---------------------------------------------------------------------------
// CSR build, two-level counting sort.
// Level 1a: per-block LDS bucket histogram -> counts[bucket][block]
// ---------------------------------------------------------------------------
__global__ __launch_bounds__(256) void k_count(const int* __restrict__ dst,
                                               int* __restrict__ counts) {
    __shared__ int h[NB];
    for (int i = threadIdx.x; i < NB; i += 256) h[i] = 0;
    __syncthreads();
    int beg = blockIdx.x * EPB;
    int end = beg + EPB; if (end > N_EDGES) end = N_EDGES;
    for (int e = beg + threadIdx.x; e < end; e += 256)
        atomicAdd(&h[dst[e] >> BSH], 1);
    __syncthreads();
    for (int i = threadIdx.x; i < NB; i += 256)
        counts[i * PART_BLOCKS + blockIdx.x] = h[i];   // bucket-major
}

// Level 1b: exclusive scan of the bucket x block matrix, in place
__global__ __launch_bounds__(1024) void k_scanM(int* __restrict__ counts) {
    __shared__ int sums[1024];
    const int t = threadIdx.x;
    const int CH = (MAT + 1023) / 1024;   // 98
    int beg = t * CH;
    int end = beg + CH; if (end > MAT) end = MAT;
    int s = 0;
    for (int i = beg; i < end; ++i) s += counts[i];
    sums[t] = s;
    __syncthreads();
    for (int o = 1; o < 1024; o <<= 1) {
        int v = (t >= o) ? sums[t - o] : 0;
        __syncthreads();
        sums[t] += v;
        __syncthreads();
    }
    int run = (t == 0) ? 0 : sums[t - 1];
    for (int i = beg; i < end; ++i) {
        int c = counts[i];
        counts[i] = run;
        run += c;
    }
}

// Level 1c: place packed (local_dst<<24 | src) into per-(block,bucket)
// contiguous sub-ranges of edges[] — sequential write streams.
__global__ __launch_bounds__(256) void k_partition(const int* __restrict__ src,
                                                   const int* __restrict__ dst,
                                                   const int* __restrict__ offs,
                                                   int* __restrict__ edges) {
    __shared__ int cur[NB];
    for (int i = threadIdx.x; i < NB; i += 256)
        cur[i] = offs[i * PART_BLOCKS + blockIdx.x];
    __syncthreads();
    int beg = blockIdx.x * EPB;
    int end = beg + EPB; if (end > N_EDGES) end = N_EDGES;
    for (int e = beg + threadIdx.x; e < end; e += 256) {
        int d = dst[e];
        int pos = atomicAdd(&cur[d >> BSH], 1);
        edges[pos] = (int)(((unsigned)(d & 255) << 24) | (unsigned)src[e]);
    }
}

// Level 2: sort one bucket IN PLACE. Stage whole region into LDS (<= CAP),
// count per-node, scan, write back sorted (masked to plain src index).
// Emits deg / cursor_end.
__global__ __launch_bounds__(256) void k_bucket_sort(const int* __restrict__ offs,
                                                     int* __restrict__ edges,
                                                     int* __restrict__ deg_g,
                                                     int* __restrict__ cend_g) {
    __shared__ int stage[CAP];
    __shared__ int cnt[256];
    __shared__ int pos[256];
    __shared__ int wsum[4];
    const int b = blockIdx.x;
    const int t = threadIdx.x;
    const int base = offs[b * PART_BLOCKS];
    const int bend = (b + 1 < NB) ? offs[(b + 1) * PART_BLOCKS] : N_EDGES;
    int n = bend - base;
    if (n > CAP) n = CAP;   // statistically impossible for this fixed input

    for (int i = t; i < n; i += 256) stage[i] = edges[base + i];
    cnt[t] = 0;
    __syncthreads();
    for (int i = t; i < n; i += 256)
        atomicAdd(&cnt[((unsigned)stage[i]) >> 24], 1);
    __syncthreads();

    // exclusive scan of 256 counts (wave shuffle scan + wave-sum fixup)
    const int lane = t & 63, wv = t >> 6;
    int v = cnt[t];
    int x = v;
    #pragma unroll
    for (int o = 1; o < 64; o <<= 1) {
        int u = __shfl_up(x, o);
        if (lane >= o) x += u;
    }
    if (lane == 63) wsum[wv] = x;
    __syncthreads();
    if (t == 0) {
        int r = 0;
        #pragma unroll
        for (int w = 0; w < 4; ++w) { int u = wsum[w]; wsum[w] = r; r += u; }
    }
    __syncthreads();
    int excl = x - v + wsum[wv];
    pos[t] = excl;
    int node = (b << 8) + t;
    if (node < N_NODES) {
        deg_g[node]  = v;
        cend_g[node] = base + excl + v;
    }
    __syncthreads();

    for (int i = t; i < n; i += 256) {
        int e  = stage[i];
        int p  = atomicAdd(&pos[((unsigned)e) >> 24], 1);
        edges[base + p] = e & 0x00FFFFFF;
    }
}

// ---------------------------------------------------------------------------
// Flash-style single-pass softmax+aggregate. One wave per node.
// ---------------------------------------------------------------------------
__global__ __launch_bounds__(256) void k_aggregate_csr(
        const int* __restrict__ sorted_src,
        const int* __restrict__ cursor_end,
        const int* __restrict__ deg,
        const float* __restrict__ hws,
        const float* __restrict__ el,
        const float* __restrict__ er,
        const float* __restrict__ bias,
        float* __restrict__ out) {
    const int wave = threadIdx.x >> 6;
    const int lane = threadIdx.x & 63;
    const int node = blockIdx.x * 4 + wave;
    if (node >= N_NODES) return;

    const int end   = cursor_end[node];
    const int dn    = deg[node];
    const int start = end - dn;

    const int h1   = lane & 3;
    const int slot = lane >> 2;
    const int hc   = lane >> 4;
    const float er1 = er[node * HEADS + h1];

    float m_p = -1e30f, l_p = 0.f;
    float m_c = -1e30f;
    float acc = 0.f;

    for (int j0 = start; j0 < end; j0 += 16) {
        int j = j0 + slot;
        int s = 0;
        float x = -1e30f;
        if (j < end) {
            s = sorted_src[j];
            float t = el[s * HEADS + h1] + er1;
            x = t > 0.f ? t : NEG_SLOPE * t;
        }
        float cm = x;
        cm = fmaxf(cm, __shfl_xor(cm, 4));
        cm = fmaxf(cm, __shfl_xor(cm, 8));
        cm = fmaxf(cm, __shfl_xor(cm, 16));
        cm = fmaxf(cm, __shfl_xor(cm, 32));
        float newm = fmaxf(m_p, cm);
        float p = __expf(x - newm);
        float cs = p;
        cs += __shfl_xor(cs, 4);
        cs += __shfl_xor(cs, 8);
        cs += __shfl_xor(cs, 16);
        cs += __shfl_xor(cs, 32);
        l_p = l_p * __expf(m_p - newm) + cs;
        m_p = newm;

        float mc_new = __shfl(m_p, hc);
        acc *= __expf(m_c - mc_new);
        m_c = mc_new;

        int cnt = end - j0; if (cnt > 16) cnt = 16;
        for (int e = 0; e < cnt; ++e) {
            float pe = __shfl(p, e * 4 + hc);
            int   se = __shfl(s, e * 4);
            acc = fmaf(pe, hws[se * HD + lane], acc);
        }
    }

    float l   = __shfl(l_p, hc);
    float inv = (l > 0.f) ? 1.f / l : 0.f;
    out[node * HD + lane] = acc * inv + bias[lane];
}

// ---------------------------------------------------------------------------
// Launch
// ---------------------------------------------------------------------------
extern "C" void kernel_launch(void* const* d_in, const int* in_sizes, int n_in,
                              void* d_out, int out_size, void* d_ws, size_t ws_size,
                              hipStream_t stream) {
    const float* feat   = (const float*)d_in[0];
    const float* W      = (const float*)d_in[1];
    const float* attn_l = (const float*)d_in[2];
    const float* attn_r = (const float*)d_in[3];
    const float* bias   = (const float*)d_in[4];
    const int*   src    = (const int*)d_in[5];
    const int*   dst    = (const int*)d_in[6];
    float* out = (float*)d_out;

    // ws (~34.8 MB): hws [N*64 f32] | el [N*4] | er [N*4] | deg [N] | cend [N]
    //                | edges [E] (partitioned then sorted in place) | counts [MAT]
    float* hws   = (float*)d_ws;
    float* el    = hws + (size_t)N_NODES * HD;
    float* er    = el + (size_t)N_NODES * HEADS;
    int*   deg    = (int*)(er + (size_t)N_NODES * HEADS);
    int*   cend   = deg + N_NODES;
    int*   edges  = cend + N_NODES;
    int*   counts = edges + N_EDGES;

    // 1) projection + fused el/er
    k_gemm_fused<<<(N_NODES + 63) / 64, 256, 0, stream>>>(feat, W, attn_l, attn_r,
                                                          hws, el, er);
    // 2) CSR build: two-level counting sort (in-place level 2)
    k_count<<<PART_BLOCKS, 256, 0, stream>>>(dst, counts);
    k_scanM<<<1, 1024, 0, stream>>>(counts);
    k_partition<<<PART_BLOCKS, 256, 0, stream>>>(src, dst, counts, edges);
    k_bucket_sort<<<NB, 256, 0, stream>>>(counts, edges, deg, cend);
    // 3) fused softmax + aggregation, one wave per node
    k_aggregate_csr<<<(N_NODES + 3) / 4, 256, 0, stream>>>(edges, cend, deg,
                                                           hws, el, er, bias, out);
}

// Round 6
// 348.012 us; speedup vs baseline: 1.4438x; 1.4438x over previous
//
#include <hip/hip_runtime.h>
#include <math.h>

#define N_NODES 100000
#define N_EDGES 1600000
#define IN_DIM  128
#define HD      64     // HEADS * OUT_DIM
#define HEADS   4
#define ODIM    16
#define NEG_SLOPE 0.2f

#define BSH 8                                   // nodes per bucket = 256
#define NB  ((N_NODES + 255) >> 8)              // 391 buckets
#define PART_BLOCKS 256
#define EPB ((N_EDGES + PART_BLOCKS - 1) / PART_BLOCKS)   // 6250
#define MAT (NB * PART_BLOCKS)                  // 100096 = 391 * 256 exactly
#define CAP 12288                               // LDS stage cap per bucket

// ---------------------------------------------------------------------------
// Kernel 1: h = feat @ W  + fused el/er epilogue.
// ---------------------------------------------------------------------------
__global__ __launch_bounds__(256) void k_gemm_fused(const float* __restrict__ feat,
                                                    const float* __restrict__ W,
                                                    const float* __restrict__ attn_l,
                                                    const float* __restrict__ attn_r,
                                                    float* __restrict__ hws,
                                                    float* __restrict__ el,
                                                    float* __restrict__ er) {
    __shared__ float sF[64][IN_DIM];
    __shared__ float sW[IN_DIM][HD];

    const int tid  = threadIdx.x;
    const int base = blockIdx.x * 64;

    for (int i = tid; i < IN_DIM * HD; i += 256) sW[i >> 6][i & 63] = W[i];
    for (int i = tid; i < 64 * IN_DIM; i += 256) {
        int n = i >> 7, k = i & 127;
        int gn = base + n;
        sF[n][k] = (gn < N_NODES) ? feat[gn * IN_DIM + k] : 0.f;
    }
    __syncthreads();

    const int cg = (tid & 15) * 4;
    const int rg = (tid >> 4) * 4;

    float acc[4][4] = {};
    for (int k = 0; k < IN_DIM; k += 4) {
        float4 w0 = *(const float4*)&sW[k + 0][cg];
        float4 w1 = *(const float4*)&sW[k + 1][cg];
        float4 w2 = *(const float4*)&sW[k + 2][cg];
        float4 w3 = *(const float4*)&sW[k + 3][cg];
        #pragma unroll
        for (int r = 0; r < 4; ++r) {
            float4 f = *(const float4*)&sF[rg + r][k];
            acc[r][0] += f.x * w0.x + f.y * w1.x + f.z * w2.x + f.w * w3.x;
            acc[r][1] += f.x * w0.y + f.y * w1.y + f.z * w2.y + f.w * w3.y;
            acc[r][2] += f.x * w0.z + f.y * w1.z + f.z * w2.z + f.w * w3.z;
            acc[r][3] += f.x * w0.w + f.y * w1.w + f.z * w2.w + f.w * w3.w;
        }
    }

    #pragma unroll
    for (int r = 0; r < 4; ++r) {
        int gn = base + rg + r;
        if (gn < N_NODES) {
            *(float4*)&hws[gn * HD + cg] =
                make_float4(acc[r][0], acc[r][1], acc[r][2], acc[r][3]);
        }
    }

    float4 al = *(const float4*)&attn_l[cg];
    float4 ar = *(const float4*)&attn_r[cg];
    const int head = (tid & 15) >> 2;
    #pragma unroll
    for (int r = 0; r < 4; ++r) {
        float pl = acc[r][0]*al.x + acc[r][1]*al.y + acc[r][2]*al.z + acc[r][3]*al.w;
        float pr = acc[r][0]*ar.x + acc[r][1]*ar.y + acc[r][2]*ar.z + acc[r][3]*ar.w;
        pl += __shfl_xor(pl, 1); pl += __shfl_xor(pl, 2);
        pr += __shfl_xor(pr, 1); pr += __shfl_xor(pr, 2);
        int gn = base + rg + r;
        if ((tid & 3) == 0 && gn < N_NODES) {
            el[gn * HEADS + head] = pl;
            er[gn * HEADS + head] = pr;
        }
    }
}

// ---------------------------------------------------------------------------
// CSR build, two-level counting sort.
// Level 1a: per-block LDS bucket histogram -> counts[bucket][block]
// ---------------------------------------------------------------------------
__global__ __launch_bounds__(256) void k_count(const int* __restrict__ dst,
                                               int* __restrict__ counts) {
    __shared__ int h[NB];
    for (int i = threadIdx.x; i < NB; i += 256) h[i] = 0;
    __syncthreads();
    int beg = blockIdx.x * EPB;
    int end = beg + EPB; if (end > N_EDGES) end = N_EDGES;
    for (int e = beg + threadIdx.x; e < end; e += 256)
        atomicAdd(&h[dst[e] >> BSH], 1);
    __syncthreads();
    for (int i = threadIdx.x; i < NB; i += 256)
        counts[i * PART_BLOCKS + blockIdx.x] = h[i];   // bucket-major
}

// ---------------------------------------------------------------------------
// Level 1b: hierarchical exclusive scan of counts[MAT], in place.
// scanA: 391 blocks x 256 -> local exclusive scan + block sums
// scanB: 1 block scans 391 block sums
// scanC: add block offset
// ---------------------------------------------------------------------------
__global__ __launch_bounds__(256) void k_scanA(int* __restrict__ counts,
                                               int* __restrict__ bsums) {
    __shared__ int wsum[4];
    const int t = threadIdx.x;
    const int i = blockIdx.x * 256 + t;
    const int lane = t & 63, wv = t >> 6;
    int v = counts[i];
    int x = v;
    #pragma unroll
    for (int o = 1; o < 64; o <<= 1) {
        int u = __shfl_up(x, o);
        if (lane >= o) x += u;
    }
    if (lane == 63) wsum[wv] = x;
    __syncthreads();
    if (t == 0) {
        int r = 0;
        #pragma unroll
        for (int w = 0; w < 4; ++w) { int u = wsum[w]; wsum[w] = r; r += u; }
    }
    __syncthreads();
    int excl = x - v + wsum[wv];
    counts[i] = excl;
    if (t == 255) bsums[blockIdx.x] = excl + v;
}

__global__ __launch_bounds__(512) void k_scanB(int* __restrict__ bsums) {
    __shared__ int s[512];
    const int t = threadIdx.x;
    int v = (t < NB) ? bsums[t] : 0;
    s[t] = v;
    __syncthreads();
    for (int o = 1; o < 512; o <<= 1) {
        int u = (t >= o) ? s[t - o] : 0;
        __syncthreads();
        s[t] += u;
        __syncthreads();
    }
    if (t < NB) bsums[t] = s[t] - v;   // exclusive
}

__global__ __launch_bounds__(256) void k_scanC(int* __restrict__ counts,
                                               const int* __restrict__ bsums) {
    int i = blockIdx.x * 256 + threadIdx.x;
    counts[i] += bsums[blockIdx.x];
}

// ---------------------------------------------------------------------------
// Level 1c: place packed (local_dst<<24 | src) into per-(block,bucket)
// contiguous sub-ranges of edges[] — sequential write streams.
// ---------------------------------------------------------------------------
__global__ __launch_bounds__(256) void k_partition(const int* __restrict__ src,
                                                   const int* __restrict__ dst,
                                                   const int* __restrict__ offs,
                                                   int* __restrict__ edges) {
    __shared__ int cur[NB];
    for (int i = threadIdx.x; i < NB; i += 256)
        cur[i] = offs[i * PART_BLOCKS + blockIdx.x];
    __syncthreads();
    int beg = blockIdx.x * EPB;
    int end = beg + EPB; if (end > N_EDGES) end = N_EDGES;
    for (int e = beg + threadIdx.x; e < end; e += 256) {
        int d = dst[e];
        int pos = atomicAdd(&cur[d >> BSH], 1);
        edges[pos] = (int)(((unsigned)(d & 255) << 24) | (unsigned)src[e]);
    }
}

// ---------------------------------------------------------------------------
// Level 2: sort one bucket IN PLACE via LDS staging. Emits deg / cursor_end.
// ---------------------------------------------------------------------------
__global__ __launch_bounds__(256) void k_bucket_sort(const int* __restrict__ offs,
                                                     int* __restrict__ edges,
                                                     int* __restrict__ deg_g,
                                                     int* __restrict__ cend_g) {
    __shared__ int stage[CAP];
    __shared__ int cnt[256];
    __shared__ int pos[256];
    __shared__ int wsum[4];
    const int b = blockIdx.x;
    const int t = threadIdx.x;
    const int base = offs[b * PART_BLOCKS];
    const int bend = (b + 1 < NB) ? offs[(b + 1) * PART_BLOCKS] : N_EDGES;
    int n = bend - base;
    if (n > CAP) n = CAP;

    for (int i = t; i < n; i += 256) stage[i] = edges[base + i];
    cnt[t] = 0;
    __syncthreads();
    for (int i = t; i < n; i += 256)
        atomicAdd(&cnt[((unsigned)stage[i]) >> 24], 1);
    __syncthreads();

    const int lane = t & 63, wv = t >> 6;
    int v = cnt[t];
    int x = v;
    #pragma unroll
    for (int o = 1; o < 64; o <<= 1) {
        int u = __shfl_up(x, o);
        if (lane >= o) x += u;
    }
    if (lane == 63) wsum[wv] = x;
    __syncthreads();
    if (t == 0) {
        int r = 0;
        #pragma unroll
        for (int w = 0; w < 4; ++w) { int u = wsum[w]; wsum[w] = r; r += u; }
    }
    __syncthreads();
    int excl = x - v + wsum[wv];
    pos[t] = excl;
    int node = (b << 8) + t;
    if (node < N_NODES) {
        deg_g[node]  = v;
        cend_g[node] = base + excl + v;
    }
    __syncthreads();

    for (int i = t; i < n; i += 256) {
        int e  = stage[i];
        int p  = atomicAdd(&pos[((unsigned)e) >> 24], 1);
        edges[base + p] = e & 0x00FFFFFF;
    }
}

// ---------------------------------------------------------------------------
// Flash-style single-pass softmax+aggregate. One wave per node.
// ---------------------------------------------------------------------------
__global__ __launch_bounds__(256) void k_aggregate_csr(
        const int* __restrict__ sorted_src,
        const int* __restrict__ cursor_end,
        const int* __restrict__ deg,
        const float* __restrict__ hws,
        const float* __restrict__ el,
        const float* __restrict__ er,
        const float* __restrict__ bias,
        float* __restrict__ out) {
    const int wave = threadIdx.x >> 6;
    const int lane = threadIdx.x & 63;
    const int node = blockIdx.x * 4 + wave;
    if (node >= N_NODES) return;

    const int end   = cursor_end[node];
    const int dn    = deg[node];
    const int start = end - dn;

    const int h1   = lane & 3;
    const int slot = lane >> 2;
    const int hc   = lane >> 4;
    const float er1 = er[node * HEADS + h1];

    float m_p = -1e30f, l_p = 0.f;
    float m_c = -1e30f;
    float acc = 0.f;

    for (int j0 = start; j0 < end; j0 += 16) {
        int j = j0 + slot;
        int s = 0;
        float x = -1e30f;
        if (j < end) {
            s = sorted_src[j];
            float t = el[s * HEADS + h1] + er1;
            x = t > 0.f ? t : NEG_SLOPE * t;
        }
        float cm = x;
        cm = fmaxf(cm, __shfl_xor(cm, 4));
        cm = fmaxf(cm, __shfl_xor(cm, 8));
        cm = fmaxf(cm, __shfl_xor(cm, 16));
        cm = fmaxf(cm, __shfl_xor(cm, 32));
        float newm = fmaxf(m_p, cm);
        float p = __expf(x - newm);
        float cs = p;
        cs += __shfl_xor(cs, 4);
        cs += __shfl_xor(cs, 8);
        cs += __shfl_xor(cs, 16);
        cs += __shfl_xor(cs, 32);
        l_p = l_p * __expf(m_p - newm) + cs;
        m_p = newm;

        float mc_new = __shfl(m_p, hc);
        acc *= __expf(m_c - mc_new);
        m_c = mc_new;

        int cnt = end - j0; if (cnt > 16) cnt = 16;
        for (int e = 0; e < cnt; ++e) {
            float pe = __shfl(p, e * 4 + hc);
            int   se = __shfl(s, e * 4);
            acc = fmaf(pe, hws[se * HD + lane], acc);
        }
    }

    float l   = __shfl(l_p, hc);
    float inv = (l > 0.f) ? 1.f / l : 0.f;
    out[node * HD + lane] = acc * inv + bias[lane];
}

// ---------------------------------------------------------------------------
// Launch
// ---------------------------------------------------------------------------
extern "C" void kernel_launch(void* const* d_in, const int* in_sizes, int n_in,
                              void* d_out, int out_size, void* d_ws, size_t ws_size,
                              hipStream_t stream) {
    const float* feat   = (const float*)d_in[0];
    const float* W      = (const float*)d_in[1];
    const float* attn_l = (const float*)d_in[2];
    const float* attn_r = (const float*)d_in[3];
    const float* bias   = (const float*)d_in[4];
    const int*   src    = (const int*)d_in[5];
    const int*   dst    = (const int*)d_in[6];
    float* out = (float*)d_out;

    // ws (~34.8 MB): hws [N*64 f32] | el [N*4] | er [N*4] | deg [N] | cend [N]
    //                | edges [E] | counts [MAT] | bsums [NB]
    float* hws   = (float*)d_ws;
    float* el    = hws + (size_t)N_NODES * HD;
    float* er    = el + (size_t)N_NODES * HEADS;
    int*   deg    = (int*)(er + (size_t)N_NODES * HEADS);
    int*   cend   = deg + N_NODES;
    int*   edges  = cend + N_NODES;
    int*   counts = edges + N_EDGES;
    int*   bsums  = counts + MAT;

    // 1) projection + fused el/er
    k_gemm_fused<<<(N_NODES + 63) / 64, 256, 0, stream>>>(feat, W, attn_l, attn_r,
                                                          hws, el, er);
    // 2) CSR build: two-level counting sort (hierarchical scan, in-place sort)
    k_count<<<PART_BLOCKS, 256, 0, stream>>>(dst, counts);
    k_scanA<<<NB, 256, 0, stream>>>(counts, bsums);
    k_scanB<<<1, 512, 0, stream>>>(bsums);
    k_scanC<<<NB, 256, 0, stream>>>(counts, bsums);
    k_partition<<<PART_BLOCKS, 256, 0, stream>>>(src, dst, counts, edges);
    k_bucket_sort<<<NB, 256, 0, stream>>>(counts, edges, deg, cend);
    // 3) fused softmax + aggregation, one wave per node
    k_aggregate_csr<<<(N_NODES + 3) / 4, 256, 0, stream>>>(edges, cend, deg,
                                                           hws, el, er, bias, out);
}

// Round 7
// 342.892 us; speedup vs baseline: 1.4654x; 1.0149x over previous
//
#include <hip/hip_runtime.h>
#include <math.h>

#define N_NODES 100000
#define N_EDGES 1600000
#define IN_DIM  128
#define HD      64     // HEADS * OUT_DIM
#define HEADS   4
#define ODIM    16
#define NEG_SLOPE 0.2f

#define BSH 8                                   // nodes per bucket = 256
#define NB  ((N_NODES + 255) >> 8)              // 391 buckets
#define PART_BLOCKS 256
#define EPB ((N_EDGES + PART_BLOCKS - 1) / PART_BLOCKS)   // 6250
#define MAT (NB * PART_BLOCKS)                  // 100096 = 391 * 256 exactly
#define CAP 12288                               // LDS stage cap per bucket

__device__ inline unsigned short f32_to_bf16_rne(float f) {
    unsigned int b = __float_as_uint(f);
    b += 0x7FFFu + ((b >> 16) & 1u);
    return (unsigned short)(b >> 16);
}
__device__ inline float bf16_to_f32(unsigned short u) {
    return __uint_as_float(((unsigned int)u) << 16);
}

// ---------------------------------------------------------------------------
// Kernel 1: h = feat @ W  + fused el/er epilogue. h stored as bf16.
// ---------------------------------------------------------------------------
__global__ __launch_bounds__(256) void k_gemm_fused(const float* __restrict__ feat,
                                                    const float* __restrict__ W,
                                                    const float* __restrict__ attn_l,
                                                    const float* __restrict__ attn_r,
                                                    unsigned short* __restrict__ hbf,
                                                    float* __restrict__ el,
                                                    float* __restrict__ er) {
    __shared__ float sF[64][IN_DIM];
    __shared__ float sW[IN_DIM][HD];

    const int tid  = threadIdx.x;
    const int base = blockIdx.x * 64;

    for (int i = tid; i < IN_DIM * HD; i += 256) sW[i >> 6][i & 63] = W[i];
    for (int i = tid; i < 64 * IN_DIM; i += 256) {
        int n = i >> 7, k = i & 127;
        int gn = base + n;
        sF[n][k] = (gn < N_NODES) ? feat[gn * IN_DIM + k] : 0.f;
    }
    __syncthreads();

    const int cg = (tid & 15) * 4;
    const int rg = (tid >> 4) * 4;

    float acc[4][4] = {};
    for (int k = 0; k < IN_DIM; k += 4) {
        float4 w0 = *(const float4*)&sW[k + 0][cg];
        float4 w1 = *(const float4*)&sW[k + 1][cg];
        float4 w2 = *(const float4*)&sW[k + 2][cg];
        float4 w3 = *(const float4*)&sW[k + 3][cg];
        #pragma unroll
        for (int r = 0; r < 4; ++r) {
            float4 f = *(const float4*)&sF[rg + r][k];
            acc[r][0] += f.x * w0.x + f.y * w1.x + f.z * w2.x + f.w * w3.x;
            acc[r][1] += f.x * w0.y + f.y * w1.y + f.z * w2.y + f.w * w3.y;
            acc[r][2] += f.x * w0.z + f.y * w1.z + f.z * w2.z + f.w * w3.z;
            acc[r][3] += f.x * w0.w + f.y * w1.w + f.z * w2.w + f.w * w3.w;
        }
    }

    #pragma unroll
    for (int r = 0; r < 4; ++r) {
        int gn = base + rg + r;
        if (gn < N_NODES) {
            ushort4 v;
            v.x = f32_to_bf16_rne(acc[r][0]);
            v.y = f32_to_bf16_rne(acc[r][1]);
            v.z = f32_to_bf16_rne(acc[r][2]);
            v.w = f32_to_bf16_rne(acc[r][3]);
            *(ushort4*)&hbf[gn * HD + cg] = v;
        }
    }

    float4 al = *(const float4*)&attn_l[cg];
    float4 ar = *(const float4*)&attn_r[cg];
    const int head = (tid & 15) >> 2;
    #pragma unroll
    for (int r = 0; r < 4; ++r) {
        float pl = acc[r][0]*al.x + acc[r][1]*al.y + acc[r][2]*al.z + acc[r][3]*al.w;
        float pr = acc[r][0]*ar.x + acc[r][1]*ar.y + acc[r][2]*ar.z + acc[r][3]*ar.w;
        pl += __shfl_xor(pl, 1); pl += __shfl_xor(pl, 2);
        pr += __shfl_xor(pr, 1); pr += __shfl_xor(pr, 2);
        int gn = base + rg + r;
        if ((tid & 3) == 0 && gn < N_NODES) {
            el[gn * HEADS + head] = pl;
            er[gn * HEADS + head] = pr;
        }
    }
}

// ---------------------------------------------------------------------------
// CSR build, two-level counting sort.
// ---------------------------------------------------------------------------
__global__ __launch_bounds__(256) void k_count(const int* __restrict__ dst,
                                               int* __restrict__ counts) {
    __shared__ int h[NB];
    for (int i = threadIdx.x; i < NB; i += 256) h[i] = 0;
    __syncthreads();
    int beg = blockIdx.x * EPB;
    int end = beg + EPB; if (end > N_EDGES) end = N_EDGES;
    for (int e = beg + threadIdx.x; e < end; e += 256)
        atomicAdd(&h[dst[e] >> BSH], 1);
    __syncthreads();
    for (int i = threadIdx.x; i < NB; i += 256)
        counts[i * PART_BLOCKS + blockIdx.x] = h[i];   // bucket-major
}

__global__ __launch_bounds__(256) void k_scanA(int* __restrict__ counts,
                                               int* __restrict__ bsums) {
    __shared__ int wsum[4];
    const int t = threadIdx.x;
    const int i = blockIdx.x * 256 + t;
    const int lane = t & 63, wv = t >> 6;
    int v = counts[i];
    int x = v;
    #pragma unroll
    for (int o = 1; o < 64; o <<= 1) {
        int u = __shfl_up(x, o);
        if (lane >= o) x += u;
    }
    if (lane == 63) wsum[wv] = x;
    __syncthreads();
    if (t == 0) {
        int r = 0;
        #pragma unroll
        for (int w = 0; w < 4; ++w) { int u = wsum[w]; wsum[w] = r; r += u; }
    }
    __syncthreads();
    int excl = x - v + wsum[wv];
    counts[i] = excl;
    if (t == 255) bsums[blockIdx.x] = excl + v;
}

__global__ __launch_bounds__(512) void k_scanB(int* __restrict__ bsums) {
    __shared__ int s[512];
    const int t = threadIdx.x;
    int v = (t < NB) ? bsums[t] : 0;
    s[t] = v;
    __syncthreads();
    for (int o = 1; o < 512; o <<= 1) {
        int u = (t >= o) ? s[t - o] : 0;
        __syncthreads();
        s[t] += u;
        __syncthreads();
    }
    if (t < NB) bsums[t] = s[t] - v;   // exclusive
}

__global__ __launch_bounds__(256) void k_scanC(int* __restrict__ counts,
                                               const int* __restrict__ bsums) {
    int i = blockIdx.x * 256 + threadIdx.x;
    counts[i] += bsums[blockIdx.x];
}

__global__ __launch_bounds__(256) void k_partition(const int* __restrict__ src,
                                                   const int* __restrict__ dst,
                                                   const int* __restrict__ offs,
                                                   int* __restrict__ edges) {
    __shared__ int cur[NB];
    for (int i = threadIdx.x; i < NB; i += 256)
        cur[i] = offs[i * PART_BLOCKS + blockIdx.x];
    __syncthreads();
    int beg = blockIdx.x * EPB;
    int end = beg + EPB; if (end > N_EDGES) end = N_EDGES;
    for (int e = beg + threadIdx.x; e < end; e += 256) {
        int d = dst[e];
        int pos = atomicAdd(&cur[d >> BSH], 1);
        edges[pos] = (int)(((unsigned)(d & 255) << 24) | (unsigned)src[e]);
    }
}

__global__ __launch_bounds__(256) void k_bucket_sort(const int* __restrict__ offs,
                                                     int* __restrict__ edges,
                                                     int* __restrict__ deg_g,
                                                     int* __restrict__ cend_g) {
    __shared__ int stage[CAP];
    __shared__ int cnt[256];
    __shared__ int pos[256];
    __shared__ int wsum[4];
    const int b = blockIdx.x;
    const int t = threadIdx.x;
    const int base = offs[b * PART_BLOCKS];
    const int bend = (b + 1 < NB) ? offs[(b + 1) * PART_BLOCKS] : N_EDGES;
    int n = bend - base;
    if (n > CAP) n = CAP;

    for (int i = t; i < n; i += 256) stage[i] = edges[base + i];
    cnt[t] = 0;
    __syncthreads();
    for (int i = t; i < n; i += 256)
        atomicAdd(&cnt[((unsigned)stage[i]) >> 24], 1);
    __syncthreads();

    const int lane = t & 63, wv = t >> 6;
    int v = cnt[t];
    int x = v;
    #pragma unroll
    for (int o = 1; o < 64; o <<= 1) {
        int u = __shfl_up(x, o);
        if (lane >= o) x += u;
    }
    if (lane == 63) wsum[wv] = x;
    __syncthreads();
    if (t == 0) {
        int r = 0;
        #pragma unroll
        for (int w = 0; w < 4; ++w) { int u = wsum[w]; wsum[w] = r; r += u; }
    }
    __syncthreads();
    int excl = x - v + wsum[wv];
    pos[t] = excl;
    int node = (b << 8) + t;
    if (node < N_NODES) {
        deg_g[node]  = v;
        cend_g[node] = base + excl + v;
    }
    __syncthreads();

    for (int i = t; i < n; i += 256) {
        int e  = stage[i];
        int p  = atomicAdd(&pos[((unsigned)e) >> 24], 1);
        edges[base + p] = e & 0x00FFFFFF;
    }
}

// ---------------------------------------------------------------------------
// Flash-style single-pass softmax+aggregate. One wave per node. h in bf16.
// ---------------------------------------------------------------------------
__global__ __launch_bounds__(256) void k_aggregate_csr(
        const int* __restrict__ sorted_src,
        const int* __restrict__ cursor_end,
        const int* __restrict__ deg,
        const unsigned short* __restrict__ hbf,
        const float* __restrict__ el,
        const float* __restrict__ er,
        const float* __restrict__ bias,
        float* __restrict__ out) {
    const int wave = threadIdx.x >> 6;
    const int lane = threadIdx.x & 63;
    const int node = blockIdx.x * 4 + wave;
    if (node >= N_NODES) return;

    const int end   = cursor_end[node];
    const int dn    = deg[node];
    const int start = end - dn;

    const int h1   = lane & 3;
    const int slot = lane >> 2;
    const int hc   = lane >> 4;
    const float er1 = er[node * HEADS + h1];

    float m_p = -1e30f, l_p = 0.f;
    float m_c = -1e30f;
    float acc = 0.f;

    for (int j0 = start; j0 < end; j0 += 16) {
        int j = j0 + slot;
        int s = 0;
        float x = -1e30f;
        if (j < end) {
            s = sorted_src[j];
            float t = el[s * HEADS + h1] + er1;
            x = t > 0.f ? t : NEG_SLOPE * t;
        }
        float cm = x;
        cm = fmaxf(cm, __shfl_xor(cm, 4));
        cm = fmaxf(cm, __shfl_xor(cm, 8));
        cm = fmaxf(cm, __shfl_xor(cm, 16));
        cm = fmaxf(cm, __shfl_xor(cm, 32));
        float newm = fmaxf(m_p, cm);
        float p = __expf(x - newm);
        float cs = p;
        cs += __shfl_xor(cs, 4);
        cs += __shfl_xor(cs, 8);
        cs += __shfl_xor(cs, 16);
        cs += __shfl_xor(cs, 32);
        l_p = l_p * __expf(m_p - newm) + cs;
        m_p = newm;

        float mc_new = __shfl(m_p, hc);
        acc *= __expf(m_c - mc_new);
        m_c = mc_new;

        int cnt = end - j0; if (cnt > 16) cnt = 16;
        for (int e = 0; e < cnt; ++e) {
            float pe = __shfl(p, e * 4 + hc);
            int   se = __shfl(s, e * 4);
            acc = fmaf(pe, bf16_to_f32(hbf[se * HD + lane]), acc);
        }
    }

    float l   = __shfl(l_p, hc);
    float inv = (l > 0.f) ? 1.f / l : 0.f;
    out[node * HD + lane] = acc * inv + bias[lane];
}

// ---------------------------------------------------------------------------
// Launch
// ---------------------------------------------------------------------------
extern "C" void kernel_launch(void* const* d_in, const int* in_sizes, int n_in,
                              void* d_out, int out_size, void* d_ws, size_t ws_size,
                              hipStream_t stream) {
    const float* feat   = (const float*)d_in[0];
    const float* W      = (const float*)d_in[1];
    const float* attn_l = (const float*)d_in[2];
    const float* attn_r = (const float*)d_in[3];
    const float* bias   = (const float*)d_in[4];
    const int*   src    = (const int*)d_in[5];
    const int*   dst    = (const int*)d_in[6];
    float* out = (float*)d_out;

    // ws (~22 MB): hbf [N*64 bf16] | el [N*4 f32] | er [N*4] | deg [N] | cend [N]
    //              | edges [E] | counts [MAT] | bsums [NB]
    unsigned short* hbf = (unsigned short*)d_ws;
    float* el    = (float*)(hbf + (size_t)N_NODES * HD);
    float* er    = el + (size_t)N_NODES * HEADS;
    int*   deg    = (int*)(er + (size_t)N_NODES * HEADS);
    int*   cend   = deg + N_NODES;
    int*   edges  = cend + N_NODES;
    int*   counts = edges + N_EDGES;
    int*   bsums  = counts + MAT;

    // 1) projection + fused el/er (h stored bf16)
    k_gemm_fused<<<(N_NODES + 63) / 64, 256, 0, stream>>>(feat, W, attn_l, attn_r,
                                                          hbf, el, er);
    // 2) CSR build: two-level counting sort (hierarchical scan, in-place sort)
    k_count<<<PART_BLOCKS, 256, 0, stream>>>(dst, counts);
    k_scanA<<<NB, 256, 0, stream>>>(counts, bsums);
    k_scanB<<<1, 512, 0, stream>>>(bsums);
    k_scanC<<<NB, 256, 0, stream>>>(counts, bsums);
    k_partition<<<PART_BLOCKS, 256, 0, stream>>>(src, dst, counts, edges);
    k_bucket_sort<<<NB, 256, 0, stream>>>(counts, edges, deg, cend);
    // 3) fused softmax + aggregation, one wave per node
    k_aggregate_csr<<<(N_NODES + 3) / 4, 256, 0, stream>>>(edges, cend, deg,
                                                           hbf, el, er, bias, out);
}

// Round 8
// 310.145 us; speedup vs baseline: 1.6201x; 1.1056x over previous
//
#include <hip/hip_runtime.h>
#include <math.h>

#define N_NODES 100000
#define N_EDGES 1600000
#define IN_DIM  128
#define HD      64     // HEADS * OUT_DIM
#define HEADS   4
#define ODIM    16
#define NEG_SLOPE 0.2f

#define BSH 8                                   // nodes per bucket = 256
#define NB  ((N_NODES + 255) >> 8)              // 391 buckets
#define PART_BLOCKS 256
#define EPB ((N_EDGES + PART_BLOCKS - 1) / PART_BLOCKS)   // 6250
#define MAT (NB * PART_BLOCKS)                  // 100096 = 391 * 256 exactly
#define CAP 12288                               // LDS stage cap per bucket

__device__ inline unsigned short f32_to_bf16_rne(float f) {
    unsigned int b = __float_as_uint(f);
    b += 0x7FFFu + ((b >> 16) & 1u);
    return (unsigned short)(b >> 16);
}
__device__ inline float bf16_to_f32(unsigned short u) {
    return __uint_as_float(((unsigned int)u) << 16);
}

// ---------------------------------------------------------------------------
// Kernel 1: h = feat @ W  + fused el/er epilogue. h stored as bf16.
// ---------------------------------------------------------------------------
__global__ __launch_bounds__(256) void k_gemm_fused(const float* __restrict__ feat,
                                                    const float* __restrict__ W,
                                                    const float* __restrict__ attn_l,
                                                    const float* __restrict__ attn_r,
                                                    unsigned short* __restrict__ hbf,
                                                    float* __restrict__ el,
                                                    float* __restrict__ er) {
    __shared__ float sF[64][IN_DIM];
    __shared__ float sW[IN_DIM][HD];

    const int tid  = threadIdx.x;
    const int base = blockIdx.x * 64;

    for (int i = tid; i < IN_DIM * HD; i += 256) sW[i >> 6][i & 63] = W[i];
    for (int i = tid; i < 64 * IN_DIM; i += 256) {
        int n = i >> 7, k = i & 127;
        int gn = base + n;
        sF[n][k] = (gn < N_NODES) ? feat[gn * IN_DIM + k] : 0.f;
    }
    __syncthreads();

    const int cg = (tid & 15) * 4;
    const int rg = (tid >> 4) * 4;

    float acc[4][4] = {};
    for (int k = 0; k < IN_DIM; k += 4) {
        float4 w0 = *(const float4*)&sW[k + 0][cg];
        float4 w1 = *(const float4*)&sW[k + 1][cg];
        float4 w2 = *(const float4*)&sW[k + 2][cg];
        float4 w3 = *(const float4*)&sW[k + 3][cg];
        #pragma unroll
        for (int r = 0; r < 4; ++r) {
            float4 f = *(const float4*)&sF[rg + r][k];
            acc[r][0] += f.x * w0.x + f.y * w1.x + f.z * w2.x + f.w * w3.x;
            acc[r][1] += f.x * w0.y + f.y * w1.y + f.z * w2.y + f.w * w3.y;
            acc[r][2] += f.x * w0.z + f.y * w1.z + f.z * w2.z + f.w * w3.z;
            acc[r][3] += f.x * w0.w + f.y * w1.w + f.z * w2.w + f.w * w3.w;
        }
    }

    #pragma unroll
    for (int r = 0; r < 4; ++r) {
        int gn = base + rg + r;
        if (gn < N_NODES) {
            ushort4 v;
            v.x = f32_to_bf16_rne(acc[r][0]);
            v.y = f32_to_bf16_rne(acc[r][1]);
            v.z = f32_to_bf16_rne(acc[r][2]);
            v.w = f32_to_bf16_rne(acc[r][3]);
            *(ushort4*)&hbf[gn * HD + cg] = v;
        }
    }

    float4 al = *(const float4*)&attn_l[cg];
    float4 ar = *(const float4*)&attn_r[cg];
    const int head = (tid & 15) >> 2;
    #pragma unroll
    for (int r = 0; r < 4; ++r) {
        float pl = acc[r][0]*al.x + acc[r][1]*al.y + acc[r][2]*al.z + acc[r][3]*al.w;
        float pr = acc[r][0]*ar.x + acc[r][1]*ar.y + acc[r][2]*ar.z + acc[r][3]*ar.w;
        pl += __shfl_xor(pl, 1); pl += __shfl_xor(pl, 2);
        pr += __shfl_xor(pr, 1); pr += __shfl_xor(pr, 2);
        int gn = base + rg + r;
        if ((tid & 3) == 0 && gn < N_NODES) {
            el[gn * HEADS + head] = pl;
            er[gn * HEADS + head] = pr;
        }
    }
}

// ---------------------------------------------------------------------------
// CSR build, two-level counting sort.
// ---------------------------------------------------------------------------
__global__ __launch_bounds__(256) void k_count(const int* __restrict__ dst,
                                               int* __restrict__ counts) {
    __shared__ int h[NB];
    for (int i = threadIdx.x; i < NB; i += 256) h[i] = 0;
    __syncthreads();
    int beg = blockIdx.x * EPB;
    int end = beg + EPB; if (end > N_EDGES) end = N_EDGES;
    for (int e = beg + threadIdx.x; e < end; e += 256)
        atomicAdd(&h[dst[e] >> BSH], 1);
    __syncthreads();
    for (int i = threadIdx.x; i < NB; i += 256)
        counts[i * PART_BLOCKS + blockIdx.x] = h[i];   // bucket-major
}

__global__ __launch_bounds__(256) void k_scanA(int* __restrict__ counts,
                                               int* __restrict__ bsums) {
    __shared__ int wsum[4];
    const int t = threadIdx.x;
    const int i = blockIdx.x * 256 + t;
    const int lane = t & 63, wv = t >> 6;
    int v = counts[i];
    int x = v;
    #pragma unroll
    for (int o = 1; o < 64; o <<= 1) {
        int u = __shfl_up(x, o);
        if (lane >= o) x += u;
    }
    if (lane == 63) wsum[wv] = x;
    __syncthreads();
    if (t == 0) {
        int r = 0;
        #pragma unroll
        for (int w = 0; w < 4; ++w) { int u = wsum[w]; wsum[w] = r; r += u; }
    }
    __syncthreads();
    int excl = x - v + wsum[wv];
    counts[i] = excl;
    if (t == 255) bsums[blockIdx.x] = excl + v;
}

__global__ __launch_bounds__(512) void k_scanB(int* __restrict__ bsums) {
    __shared__ int s[512];
    const int t = threadIdx.x;
    int v = (t < NB) ? bsums[t] : 0;
    s[t] = v;
    __syncthreads();
    for (int o = 1; o < 512; o <<= 1) {
        int u = (t >= o) ? s[t - o] : 0;
        __syncthreads();
        s[t] += u;
        __syncthreads();
    }
    if (t < NB) bsums[t] = s[t] - v;   // exclusive
}

__global__ __launch_bounds__(256) void k_scanC(int* __restrict__ counts,
                                               const int* __restrict__ bsums) {
    int i = blockIdx.x * 256 + threadIdx.x;
    counts[i] += bsums[blockIdx.x];
}

__global__ __launch_bounds__(256) void k_partition(const int* __restrict__ src,
                                                   const int* __restrict__ dst,
                                                   const int* __restrict__ offs,
                                                   int* __restrict__ edges) {
    __shared__ int cur[NB];
    for (int i = threadIdx.x; i < NB; i += 256)
        cur[i] = offs[i * PART_BLOCKS + blockIdx.x];
    __syncthreads();
    int beg = blockIdx.x * EPB;
    int end = beg + EPB; if (end > N_EDGES) end = N_EDGES;
    for (int e = beg + threadIdx.x; e < end; e += 256) {
        int d = dst[e];
        int pos = atomicAdd(&cur[d >> BSH], 1);
        edges[pos] = (int)(((unsigned)(d & 255) << 24) | (unsigned)src[e]);
    }
}

__global__ __launch_bounds__(256) void k_bucket_sort(const int* __restrict__ offs,
                                                     int* __restrict__ edges,
                                                     int* __restrict__ deg_g,
                                                     int* __restrict__ cend_g) {
    __shared__ int stage[CAP];
    __shared__ int cnt[256];
    __shared__ int pos[256];
    __shared__ int wsum[4];
    const int b = blockIdx.x;
    const int t = threadIdx.x;
    const int base = offs[b * PART_BLOCKS];
    const int bend = (b + 1 < NB) ? offs[(b + 1) * PART_BLOCKS] : N_EDGES;
    int n = bend - base;
    if (n > CAP) n = CAP;

    for (int i = t; i < n; i += 256) stage[i] = edges[base + i];
    cnt[t] = 0;
    __syncthreads();
    for (int i = t; i < n; i += 256)
        atomicAdd(&cnt[((unsigned)stage[i]) >> 24], 1);
    __syncthreads();

    const int lane = t & 63, wv = t >> 6;
    int v = cnt[t];
    int x = v;
    #pragma unroll
    for (int o = 1; o < 64; o <<= 1) {
        int u = __shfl_up(x, o);
        if (lane >= o) x += u;
    }
    if (lane == 63) wsum[wv] = x;
    __syncthreads();
    if (t == 0) {
        int r = 0;
        #pragma unroll
        for (int w = 0; w < 4; ++w) { int u = wsum[w]; wsum[w] = r; r += u; }
    }
    __syncthreads();
    int excl = x - v + wsum[wv];
    pos[t] = excl;
    int node = (b << 8) + t;
    if (node < N_NODES) {
        deg_g[node]  = v;
        cend_g[node] = base + excl + v;
    }
    __syncthreads();

    for (int i = t; i < n; i += 256) {
        int e  = stage[i];
        int p  = atomicAdd(&pos[((unsigned)e) >> 24], 1);
        edges[base + p] = e & 0x00FFFFFF;
    }
}

// ---------------------------------------------------------------------------
// Flash-style softmax+aggregate, 4 NODES PER WAVE interleaved.
// Four independent per-node chains (load, gather, shfl-reduce, gather+fma)
// give the scheduler cross-node ILP to hide latency. Staged so the 4
// sorted_src loads and then the 4 el gathers issue back-to-back.
// ---------------------------------------------------------------------------
#define NPW 4   // nodes per wave
__global__ __launch_bounds__(256) void k_aggregate_csr(
        const int* __restrict__ sorted_src,
        const int* __restrict__ cursor_end,
        const int* __restrict__ deg,
        const unsigned short* __restrict__ hbf,
        const float* __restrict__ el,
        const float* __restrict__ er,
        const float* __restrict__ bias,
        float* __restrict__ out) {
    const int wave = threadIdx.x >> 6;
    const int lane = threadIdx.x & 63;
    const int n0   = (blockIdx.x * 4 + wave) * NPW;
    if (n0 >= N_NODES) return;

    const int h1   = lane & 3;
    const int slot = lane >> 2;
    const int hc   = lane >> 4;

    int   endv[NPW], j0[NPW];
    float er1[NPW];
    float m_p[NPW], l_p[NPW], m_c[NPW];
    float acc0[NPW], acc1[NPW];

    #pragma unroll
    for (int k = 0; k < NPW; ++k) {
        int nk = n0 + k;
        bool ok = nk < N_NODES;
        endv[k] = ok ? cursor_end[nk] : 0;
        int dn  = ok ? deg[nk] : 0;
        j0[k]   = endv[k] - dn;
        er1[k]  = ok ? er[nk * HEADS + h1] : 0.f;
        m_p[k] = -1e30f; l_p[k] = 0.f; m_c[k] = -1e30f;
        acc0[k] = 0.f; acc1[k] = 0.f;
    }

    for (;;) {
        bool any = false;
        #pragma unroll
        for (int k = 0; k < NPW; ++k) any |= (j0[k] < endv[k]);
        if (!any) break;

        int   sK[NPW];
        float xK[NPW];
        // stage A: issue all sorted_src loads
        #pragma unroll
        for (int k = 0; k < NPW; ++k) {
            int j = j0[k] + slot;
            sK[k] = (j0[k] < endv[k] && j < endv[k]) ? sorted_src[j] : -1;
        }
        // stage B: issue all el gathers
        #pragma unroll
        for (int k = 0; k < NPW; ++k) {
            if (sK[k] >= 0) {
                float t = el[sK[k] * HEADS + h1] + er1[k];
                xK[k] = t > 0.f ? t : NEG_SLOPE * t;
            } else {
                xK[k] = -1e30f;
            }
        }
        // stage C: per-node shfl reductions (4 independent chains)
        float pK[NPW];
        #pragma unroll
        for (int k = 0; k < NPW; ++k) {
            if (j0[k] >= endv[k]) { pK[k] = 0.f; continue; }
            float cm = xK[k];
            cm = fmaxf(cm, __shfl_xor(cm, 4));
            cm = fmaxf(cm, __shfl_xor(cm, 8));
            cm = fmaxf(cm, __shfl_xor(cm, 16));
            cm = fmaxf(cm, __shfl_xor(cm, 32));
            float newm = fmaxf(m_p[k], cm);
            float p = __expf(xK[k] - newm);
            float cs = p;
            cs += __shfl_xor(cs, 4);
            cs += __shfl_xor(cs, 8);
            cs += __shfl_xor(cs, 16);
            cs += __shfl_xor(cs, 32);
            l_p[k] = l_p[k] * __expf(m_p[k] - newm) + cs;
            m_p[k] = newm;
            float mc_new = __shfl(m_p[k], hc);
            float rs = __expf(m_c[k] - mc_new);
            acc0[k] *= rs; acc1[k] *= rs;
            m_c[k] = mc_new;
            pK[k] = p;
        }
        // stage D: per-node gather+fma (16-deep MLP each, 2 acc chains)
        #pragma unroll
        for (int k = 0; k < NPW; ++k) {
            if (j0[k] >= endv[k]) continue;
            int cnt = endv[k] - j0[k]; if (cnt > 16) cnt = 16;
            for (int e = 0; e < cnt; e += 2) {
                float pe0 = __shfl(pK[k], e * 4 + hc);
                int   se0 = __shfl(sK[k], e * 4);
                acc0[k] = fmaf(pe0, bf16_to_f32(hbf[se0 * HD + lane]), acc0[k]);
                if (e + 1 < cnt) {
                    float pe1 = __shfl(pK[k], (e + 1) * 4 + hc);
                    int   se1 = __shfl(sK[k], (e + 1) * 4);
                    acc1[k] = fmaf(pe1, bf16_to_f32(hbf[se1 * HD + lane]), acc1[k]);
                }
            }
            j0[k] += 16;
        }
    }

    const float bl = bias[lane];
    #pragma unroll
    for (int k = 0; k < NPW; ++k) {
        int nk = n0 + k;
        if (nk >= N_NODES) continue;
        float l   = __shfl(l_p[k], hc);
        float inv = (l > 0.f) ? 1.f / l : 0.f;
        out[nk * HD + lane] = (acc0[k] + acc1[k]) * inv + bl;
    }
}

// ---------------------------------------------------------------------------
// Launch
// ---------------------------------------------------------------------------
extern "C" void kernel_launch(void* const* d_in, const int* in_sizes, int n_in,
                              void* d_out, int out_size, void* d_ws, size_t ws_size,
                              hipStream_t stream) {
    const float* feat   = (const float*)d_in[0];
    const float* W      = (const float*)d_in[1];
    const float* attn_l = (const float*)d_in[2];
    const float* attn_r = (const float*)d_in[3];
    const float* bias   = (const float*)d_in[4];
    const int*   src    = (const int*)d_in[5];
    const int*   dst    = (const int*)d_in[6];
    float* out = (float*)d_out;

    // ws (~22 MB): hbf [N*64 bf16] | el [N*4 f32] | er [N*4] | deg [N] | cend [N]
    //              | edges [E] | counts [MAT] | bsums [NB]
    unsigned short* hbf = (unsigned short*)d_ws;
    float* el    = (float*)(hbf + (size_t)N_NODES * HD);
    float* er    = el + (size_t)N_NODES * HEADS;
    int*   deg    = (int*)(er + (size_t)N_NODES * HEADS);
    int*   cend   = deg + N_NODES;
    int*   edges  = cend + N_NODES;
    int*   counts = edges + N_EDGES;
    int*   bsums  = counts + MAT;

    // 1) projection + fused el/er (h stored bf16)
    k_gemm_fused<<<(N_NODES + 63) / 64, 256, 0, stream>>>(feat, W, attn_l, attn_r,
                                                          hbf, el, er);
    // 2) CSR build: two-level counting sort (hierarchical scan, in-place sort)
    k_count<<<PART_BLOCKS, 256, 0, stream>>>(dst, counts);
    k_scanA<<<NB, 256, 0, stream>>>(counts, bsums);
    k_scanB<<<1, 512, 0, stream>>>(bsums);
    k_scanC<<<NB, 256, 0, stream>>>(counts, bsums);
    k_partition<<<PART_BLOCKS, 256, 0, stream>>>(src, dst, counts, edges);
    k_bucket_sort<<<NB, 256, 0, stream>>>(counts, edges, deg, cend);
    // 3) fused softmax + aggregation, 4 nodes per wave
    const int nodes_per_block = 4 * NPW;   // 4 waves x 4 nodes
    k_aggregate_csr<<<(N_NODES + nodes_per_block - 1) / nodes_per_block, 256, 0, stream>>>(
        edges, cend, deg, hbf, el, er, bias, out);
}